// Round 7
// baseline (121.513 us; speedup 1.0000x reference)
//
#include <hip/hip_runtime.h>

#define EPS 1e-6f
#define NT  64    // ONE wave per block: wave-private LDS, no cross-wave barriers

__device__ __forceinline__ float fsqrt_fast(float x) {
    return __builtin_amdgcn_sqrtf(x);      // v_sqrt_f32, ~1 ulp; threshold 2.4e-2
}
__device__ __forceinline__ float fdiv_fast(float a, float b) {
    return a * __builtin_amdgcn_rcpf(b);   // v_rcp_f32 + mul, replaces IEEE div seq
}
__device__ __forceinline__ float norm2f(float dx, float dy) {
    return fsqrt_fast(dx * dx + dy * dy);
}

// Scalar-only 8-way select (cndmask chain). Array version defeated SROA ->
// scratch spills (R1-R3: VGPR_Count=28, 20MB scratch WRITE leakage).
__device__ __forceinline__ float sel8s(int k, float v0, float v1, float v2,
                                       float v3, float v4, float v5, float v6,
                                       float v7) {
    float r = v0;
    r = (k == 1) ? v1 : r;
    r = (k == 2) ? v2 : r;
    r = (k == 3) ? v3 : r;
    r = (k == 4) ? v4 : r;
    r = (k == 5) ? v5 : r;
    r = (k == 6) ? v6 : r;
    r = (k == 7) ? v7 : r;
    return r;
}

__global__ __launch_bounds__(64) void gsc_loss_kernel(
    const float* __restrict__ pred, const float* __restrict__ gt,
    float2* __restrict__ partials, int B)
{
    // 64 rows x 7 float4 (112 B padded: gcd(7,8)=1 -> conflict-free
    // ds_read_b128) x 2 tensors = 14,336 B -> 11 blocks(waves)/CU.
    // Single-wave block: __syncthreads is a wave-local fence, no cross-wave
    // lockstep (R4-R6's 3 block-wide barriers serialized 4 waves/block).
    __shared__ float4 sT[NT * 7 * 2];
    const int t = threadIdx.x;             // 0..63
    const size_t rowBase = (size_t)blockIdx.x * NT;

    // ---- all 12 coalesced global loads in flight at once (12 KB/wave) ----
    const float4* p4 = reinterpret_cast<const float4*>(pred) + rowBase * 6;
    const float4* g4 = reinterpret_cast<const float4*>(gt)   + rowBase * 6;
    float4 pr0 = p4[t + 0 * NT], pr1 = p4[t + 1 * NT], pr2 = p4[t + 2 * NT];
    float4 pr3 = p4[t + 3 * NT], pr4 = p4[t + 4 * NT], pr5 = p4[t + 5 * NT];
    float4 gr0 = g4[t + 0 * NT], gr1 = g4[t + 1 * NT], gr2 = g4[t + 2 * NT];
    float4 gr3 = g4[t + 3 * NT], gr4 = g4[t + 4 * NT], gr5 = g4[t + 5 * NT];

    // chunk f = t + i*NT  ->  slot 7*(f/6) + f%6
#define SLOT(i) (7 * ((t + (i) * NT) / 6) + ((t + (i) * NT) % 6))
    sT[SLOT(0)]          = pr0; sT[SLOT(1)]          = pr1;
    sT[SLOT(2)]          = pr2; sT[SLOT(3)]          = pr3;
    sT[SLOT(4)]          = pr4; sT[SLOT(5)]          = pr5;
    sT[NT * 7 + SLOT(0)] = gr0; sT[NT * 7 + SLOT(1)] = gr1;
    sT[NT * 7 + SLOT(2)] = gr2; sT[NT * 7 + SLOT(3)] = gr3;
    sT[NT * 7 + SLOT(4)] = gr4; sT[NT * 7 + SLOT(5)] = gr5;
#undef SLOT
    __syncthreads();                       // single-wave barrier: near-free

    float4 pA = sT[t * 7 + 0], pB = sT[t * 7 + 1], pC = sT[t * 7 + 2];
    float4 pD = sT[t * 7 + 3], pE = sT[t * 7 + 4], pF = sT[t * 7 + 5];
    float4 gA = sT[NT * 7 + t * 7 + 0], gB = sT[NT * 7 + t * 7 + 1];
    float4 gC = sT[NT * 7 + t * 7 + 2], gD = sT[NT * 7 + t * 7 + 3];
    float4 gE = sT[NT * 7 + t * 7 + 4], gF = sT[NT * 7 + t * 7 + 5];

    float px0 = pA.x, py0 = pA.y, pz0 = pA.z;
    float px1 = pA.w, py1 = pB.x, pz1 = pB.y;
    float px2 = pB.z, py2 = pB.w, pz2 = pC.x;
    float px3 = pC.y, py3 = pC.z, pz3 = pC.w;
    float px4 = pD.x, py4 = pD.y, pz4 = pD.z;
    float px5 = pD.w, py5 = pE.x, pz5 = pE.y;
    float px6 = pE.z, py6 = pE.w, pz6 = pF.x;
    float px7 = pF.y, py7 = pF.z, pz7 = pF.w;

    float gx0 = gA.x, gy0 = gA.y, gz0 = gA.z;
    float gx1 = gA.w, gy1 = gB.x, gz1 = gB.y;
    float gx2 = gB.z, gy2 = gB.w, gz2 = gC.x;
    float gx3 = gC.y, gy3 = gC.z, gz3 = gC.w;
    float gx4 = gD.x, gy4 = gD.y, gz4 = gD.z;
    float gx5 = gD.w, gy5 = gE.x, gz5 = gE.y;
    float gx6 = gE.z, gy6 = gE.w, gz6 = gF.x;
    float gx7 = gF.y, gy7 = gF.z, gz7 = gF.w;

    float L = 0.0f, vflag = 0.0f;

    unsigned mask = 0;
    mask |= (pz0 > 0.5f && gz0 > 0.5f) ? 1u   : 0u;
    mask |= (pz1 > 0.5f && gz1 > 0.5f) ? 2u   : 0u;
    mask |= (pz2 > 0.5f && gz2 > 0.5f) ? 4u   : 0u;
    mask |= (pz3 > 0.5f && gz3 > 0.5f) ? 8u   : 0u;
    mask |= (pz4 > 0.5f && gz4 > 0.5f) ? 16u  : 0u;
    mask |= (pz5 > 0.5f && gz5 > 0.5f) ? 32u  : 0u;
    mask |= (pz6 > 0.5f && gz6 > 0.5f) ? 64u  : 0u;
    mask |= (pz7 > 0.5f && gz7 > 0.5f) ? 128u : 0u;

    if ((rowBase + t) < (size_t)B && __popc(mask) >= 4) {
        vflag = 1.0f;

        unsigned m = mask;
        int k0 = __ffs(m) - 1; m &= m - 1;
        int k1 = __ffs(m) - 1; m &= m - 1;
        int k2 = __ffs(m) - 1; m &= m - 1;
        int k3 = __ffs(m) - 1;

        float P1x = sel8s(k0, px0, px1, px2, px3, px4, px5, px6, px7);
        float P1y = sel8s(k0, py0, py1, py2, py3, py4, py5, py6, py7);
        float G1x = sel8s(k0, gx0, gx1, gx2, gx3, gx4, gx5, gx6, gx7);
        float G1y = sel8s(k0, gy0, gy1, gy2, gy3, gy4, gy5, gy6, gy7);
        float P2x = sel8s(k1, px0, px1, px2, px3, px4, px5, px6, px7);
        float P2y = sel8s(k1, py0, py1, py2, py3, py4, py5, py6, py7);
        float G2x = sel8s(k1, gx0, gx1, gx2, gx3, gx4, gx5, gx6, gx7);
        float G2y = sel8s(k1, gy0, gy1, gy2, gy3, gy4, gy5, gy6, gy7);
        float P3x = sel8s(k2, px0, px1, px2, px3, px4, px5, px6, px7);
        float P3y = sel8s(k2, py0, py1, py2, py3, py4, py5, py6, py7);
        float G3x = sel8s(k2, gx0, gx1, gx2, gx3, gx4, gx5, gx6, gx7);
        float G3y = sel8s(k2, gy0, gy1, gy2, gy3, gy4, gy5, gy6, gy7);
        float P4x = sel8s(k3, px0, px1, px2, px3, px4, px5, px6, px7);
        float P4y = sel8s(k3, py0, py1, py2, py3, py4, py5, py6, py7);
        float G4x = sel8s(k3, gx0, gx1, gx2, gx3, gx4, gx5, gx6, gx7);
        float G4y = sel8s(k3, gy0, gy1, gy2, gy3, gy4, gy5, gy6, gy7);

        // ---- L_shape ----
        float pd31x = P3x - P1x, pd31y = P3y - P1y;
        float pd42x = P4x - P2x, pd42y = P4y - P2y;
        float gd31x = G3x - G1x, gd31y = G3y - G1y;
        float gd42x = G4x - G2x, gd42y = G4y - G2y;
        float pred_cr = fdiv_fast(norm2f(pd31x, pd31y), norm2f(pd42x, pd42y) + EPS);
        float gt_cr   = fdiv_fast(norm2f(gd31x, gd31y), norm2f(gd42x, gd42y) + EPS);
        float L_shape = fabsf(pred_cr - gt_cr);

        // ---- L_edge ----
        float v12x = P2x - P1x, v12y = P2y - P1y;
        float v23x = P3x - P2x, v23y = P3y - P2y;
        float v34x = P4x - P3x, v34y = P4y - P3y;
        float v41x = P1x - P4x, v41y = P1y - P4y;
        float l12 = norm2f(v12x, v12y), l23 = norm2f(v23x, v23y);
        float l34 = norm2f(v34x, v34y), l41 = norm2f(v41x, v41y);
        float par1 = fdiv_fast(fabsf(l12 - l34), l12 + l34 + EPS);
        float par2 = fdiv_fast(fabsf(l23 - l41), l23 + l41 + EPS);
        float dot1 = fabsf(fdiv_fast(v12x * v41x + v12y * v41y, l12 * l41 + EPS));
        float dot2 = fabsf(fdiv_fast(v12x * v23x + v12y * v23y, l12 * l23 + EPS));
        float dot3 = fabsf(fdiv_fast(v23x * v34x + v23y * v34y, l23 * l34 + EPS));
        float dot4 = fabsf(fdiv_fast(v34x * v41x + v34y * v41y, l34 * l41 + EPS));
        float L_edge = 0.5f * (par1 + par2) + 0.25f * (dot1 + dot2 + dot3 + dot4);

        // ---- L_pos ----
        float dist = 0.25f * (norm2f(P1x - G1x, P1y - G1y) +
                              norm2f(P2x - G2x, P2y - G2y) +
                              norm2f(P3x - G3x, P3y - G3y) +
                              norm2f(P4x - G4x, P4y - G4y));

        float p21x = P2x - P1x, p21y = P2y - P1y;
        float p41x = P4x - P1x, p41y = P4y - P1y;
        float g21x = G2x - G1x, g21y = G2y - G1y;
        float g41x = G4x - G1x, g41y = G4y - G1y;
        float pred_area = 0.5f * fabsf(p21x * pd31y - p21y * pd31x)
                        + 0.5f * fabsf(pd31x * p41y - pd31y * p41x);
        float gt_area   = 0.5f * fabsf(g21x * gd31y - g21y * gd31x)
                        + 0.5f * fabsf(gd31x * g41y - gd31y * g41x);
        float area_ratio = fdiv_fast(fabsf(pred_area - gt_area), gt_area + EPS);

        float mpx = 0.25f * (P1x + P2x + P3x + P4x);
        float mpy = 0.25f * (P1y + P2y + P3y + P4y);
        float mgx = 0.25f * (G1x + G2x + G3x + G4x);
        float mgy = 0.25f * (G1y + G2y + G3y + G4y);
        float rel_cons = 0.25f *
            (norm2f((P1x - mpx) - (G1x - mgx), (P1y - mpy) - (G1y - mgy)) +
             norm2f((P2x - mpx) - (G2x - mgx), (P2y - mpy) - (G2y - mgy)) +
             norm2f((P3x - mpx) - (G3x - mgx), (P3y - mpy) - (G3y - mgy)) +
             norm2f((P4x - mpx) - (G4x - mgx), (P4y - mpy) - (G4y - mgy)));

        float L_pos = 0.4f * dist + 0.3f * area_ratio + 0.3f * rel_cons;
        L = 0.4f * L_shape + 0.3f * L_edge + 0.3f * L_pos;
    }

    // ---- wave64 shuffle reduce -> one partial store per block(wave) ----
#pragma unroll
    for (int off = 32; off > 0; off >>= 1) {
        L     += __shfl_down(L, off, 64);
        vflag += __shfl_down(vflag, off, 64);
    }
    if (t == 0) partials[blockIdx.x] = make_float2(L, vflag);
}

// Stage 2: reduce nPart partials in one block, write final scalar.
__global__ __launch_bounds__(256) void gsc_reduce_kernel(
    const float2* __restrict__ partials, int nPart, float* __restrict__ out)
{
    float sLsum = 0.0f, sVsum = 0.0f;
    for (int i = threadIdx.x; i < nPart; i += 256) {
        float2 p = partials[i];
        sLsum += p.x;
        sVsum += p.y;
    }
#pragma unroll
    for (int off = 32; off > 0; off >>= 1) {
        sLsum += __shfl_down(sLsum, off, 64);
        sVsum += __shfl_down(sVsum, off, 64);
    }
    __shared__ float sL[4], sV[4];
    int lane = threadIdx.x & 63;
    int wv   = threadIdx.x >> 6;
    if (lane == 0) { sL[wv] = sLsum; sV[wv] = sVsum; }
    __syncthreads();
    if (threadIdx.x == 0) {
        float tL = sL[0] + sL[1] + sL[2] + sL[3];
        float tV = sV[0] + sV[1] + sV[2] + sV[3];
        out[0] = (tV > 0.0f) ? (tL / tV) : 0.0f;
    }
}

extern "C" void kernel_launch(void* const* d_in, const int* in_sizes, int n_in,
                              void* d_out, int out_size, void* d_ws, size_t ws_size,
                              hipStream_t stream) {
    const float* pred = (const float*)d_in[0];
    const float* gt   = (const float*)d_in[1];
    float* out = (float*)d_out;
    float2* partials = (float2*)d_ws;   // one float2 per block (64 KB @ 8192)

    int B = in_sizes[0] / 24;           // 524288 (multiple of 64)
    int grid = (B + NT - 1) / NT;       // 8192

    gsc_loss_kernel<<<grid, NT, 0, stream>>>(pred, gt, partials, B);
    gsc_reduce_kernel<<<1, 256, 0, stream>>>(partials, grid, out);
}

// Round 8
// 116.529 us; speedup vs baseline: 1.0428x; 1.0428x over previous
//
#include <hip/hip_runtime.h>

#define EPS 1e-6f
#define NT  256   // threads per block == rows per block (B % 256 == 0)

__device__ __forceinline__ float fsqrt_fast(float x) {
    return __builtin_amdgcn_sqrtf(x);      // v_sqrt_f32, ~1 ulp; threshold 2.4e-2
}
__device__ __forceinline__ float fdiv_fast(float a, float b) {
    return a * __builtin_amdgcn_rcpf(b);   // v_rcp_f32 + mul, replaces IEEE div seq
}
__device__ __forceinline__ float norm2f(float dx, float dy) {
    return fsqrt_fast(dx * dx + dy * dy);
}

// Scalar-only 8-way select (cndmask chain). Array version defeated SROA ->
// scratch spills (R1-R3: VGPR_Count=28, 20MB scratch WRITE leakage).
__device__ __forceinline__ float sel8s(int k, float v0, float v1, float v2,
                                       float v3, float v4, float v5, float v6,
                                       float v7) {
    float r = v0;
    r = (k == 1) ? v1 : r;
    r = (k == 2) ? v2 : r;
    r = (k == 3) ? v3 : r;
    r = (k == 4) ? v4 : r;
    r = (k == 5) ? v5 : r;
    r = (k == 6) ? v6 : r;
    r = (k == 7) ? v7 : r;
    return r;
}

// R6 structure (best: 20 waves/CU; R7's 1-wave blocks halved occupancy and
// regressed) + fast-math only.
__global__ __launch_bounds__(256) void gsc_loss_kernel(
    const float* __restrict__ pred, const float* __restrict__ gt,
    float2* __restrict__ partials, int B)
{
    // Rows padded to 7 float4 (112 B): row-read slot 7t+c, gcd(7,8)=1 ->
    // conflict-free ds_read_b128. One buffer, two phases (28.7 KB, 5 blk/CU).
    __shared__ float4 sT[NT * 7];
    const int t = threadIdx.x;
    const size_t rowBase = (size_t)blockIdx.x * NT;

    // ---- all 12 coalesced global loads in flight at once (12 KB/wave) ----
    const float4* p4 = reinterpret_cast<const float4*>(pred) + rowBase * 6;
    const float4* g4 = reinterpret_cast<const float4*>(gt)   + rowBase * 6;
    float4 pr0 = p4[t + 0 * NT], pr1 = p4[t + 1 * NT], pr2 = p4[t + 2 * NT];
    float4 pr3 = p4[t + 3 * NT], pr4 = p4[t + 4 * NT], pr5 = p4[t + 5 * NT];
    float4 gr0 = g4[t + 0 * NT], gr1 = g4[t + 1 * NT], gr2 = g4[t + 2 * NT];
    float4 gr3 = g4[t + 3 * NT], gr4 = g4[t + 4 * NT], gr5 = g4[t + 5 * NT];

    // staging slot for loaded chunk i: f = t + i*NT, slot = 7*(f/6) + f%6
#define SLOT(i) (7 * ((t + (i) * NT) / 6) + ((t + (i) * NT) % 6))
    // ---- phase 1: pred through LDS -> 24 named scalars ----
    sT[SLOT(0)] = pr0; sT[SLOT(1)] = pr1; sT[SLOT(2)] = pr2;
    sT[SLOT(3)] = pr3; sT[SLOT(4)] = pr4; sT[SLOT(5)] = pr5;
    __syncthreads();
    float4 pA = sT[t * 7 + 0], pB = sT[t * 7 + 1], pC = sT[t * 7 + 2];
    float4 pD = sT[t * 7 + 3], pE = sT[t * 7 + 4], pF = sT[t * 7 + 5];

    float px0 = pA.x, py0 = pA.y, pz0 = pA.z;
    float px1 = pA.w, py1 = pB.x, pz1 = pB.y;
    float px2 = pB.z, py2 = pB.w, pz2 = pC.x;
    float px3 = pC.y, py3 = pC.z, pz3 = pC.w;
    float px4 = pD.x, py4 = pD.y, pz4 = pD.z;
    float px5 = pD.w, py5 = pE.x, pz5 = pE.y;
    float px6 = pE.z, py6 = pE.w, pz6 = pF.x;
    float px7 = pF.y, py7 = pF.z, pz7 = pF.w;
    __syncthreads();                 // all phase-1 reads done before overwrite

    // ---- phase 2: gt through the same buffer (data already in registers) ----
    sT[SLOT(0)] = gr0; sT[SLOT(1)] = gr1; sT[SLOT(2)] = gr2;
    sT[SLOT(3)] = gr3; sT[SLOT(4)] = gr4; sT[SLOT(5)] = gr5;
#undef SLOT
    __syncthreads();
    float4 gA = sT[t * 7 + 0], gB = sT[t * 7 + 1], gC = sT[t * 7 + 2];
    float4 gD = sT[t * 7 + 3], gE = sT[t * 7 + 4], gF = sT[t * 7 + 5];

    float gx0 = gA.x, gy0 = gA.y, gz0 = gA.z;
    float gx1 = gA.w, gy1 = gB.x, gz1 = gB.y;
    float gx2 = gB.z, gy2 = gB.w, gz2 = gC.x;
    float gx3 = gC.y, gy3 = gC.z, gz3 = gC.w;
    float gx4 = gD.x, gy4 = gD.y, gz4 = gD.z;
    float gx5 = gD.w, gy5 = gE.x, gz5 = gE.y;
    float gx6 = gE.z, gy6 = gE.w, gz6 = gF.x;
    float gx7 = gF.y, gy7 = gF.z, gz7 = gF.w;

    float L = 0.0f, vflag = 0.0f;

    unsigned mask = 0;
    mask |= (pz0 > 0.5f && gz0 > 0.5f) ? 1u   : 0u;
    mask |= (pz1 > 0.5f && gz1 > 0.5f) ? 2u   : 0u;
    mask |= (pz2 > 0.5f && gz2 > 0.5f) ? 4u   : 0u;
    mask |= (pz3 > 0.5f && gz3 > 0.5f) ? 8u   : 0u;
    mask |= (pz4 > 0.5f && gz4 > 0.5f) ? 16u  : 0u;
    mask |= (pz5 > 0.5f && gz5 > 0.5f) ? 32u  : 0u;
    mask |= (pz6 > 0.5f && gz6 > 0.5f) ? 64u  : 0u;
    mask |= (pz7 > 0.5f && gz7 > 0.5f) ? 128u : 0u;

    if ((rowBase + t) < (size_t)B && __popc(mask) >= 4) {
        vflag = 1.0f;

        unsigned m = mask;
        int k0 = __ffs(m) - 1; m &= m - 1;
        int k1 = __ffs(m) - 1; m &= m - 1;
        int k2 = __ffs(m) - 1; m &= m - 1;
        int k3 = __ffs(m) - 1;

        float P1x = sel8s(k0, px0, px1, px2, px3, px4, px5, px6, px7);
        float P1y = sel8s(k0, py0, py1, py2, py3, py4, py5, py6, py7);
        float G1x = sel8s(k0, gx0, gx1, gx2, gx3, gx4, gx5, gx6, gx7);
        float G1y = sel8s(k0, gy0, gy1, gy2, gy3, gy4, gy5, gy6, gy7);
        float P2x = sel8s(k1, px0, px1, px2, px3, px4, px5, px6, px7);
        float P2y = sel8s(k1, py0, py1, py2, py3, py4, py5, py6, py7);
        float G2x = sel8s(k1, gx0, gx1, gx2, gx3, gx4, gx5, gx6, gx7);
        float G2y = sel8s(k1, gy0, gy1, gy2, gy3, gy4, gy5, gy6, gy7);
        float P3x = sel8s(k2, px0, px1, px2, px3, px4, px5, px6, px7);
        float P3y = sel8s(k2, py0, py1, py2, py3, py4, py5, py6, py7);
        float G3x = sel8s(k2, gx0, gx1, gx2, gx3, gx4, gx5, gx6, gx7);
        float G3y = sel8s(k2, gy0, gy1, gy2, gy3, gy4, gy5, gy6, gy7);
        float P4x = sel8s(k3, px0, px1, px2, px3, px4, px5, px6, px7);
        float P4y = sel8s(k3, py0, py1, py2, py3, py4, py5, py6, py7);
        float G4x = sel8s(k3, gx0, gx1, gx2, gx3, gx4, gx5, gx6, gx7);
        float G4y = sel8s(k3, gy0, gy1, gy2, gy3, gy4, gy5, gy6, gy7);

        // ---- L_shape ----
        float pd31x = P3x - P1x, pd31y = P3y - P1y;
        float pd42x = P4x - P2x, pd42y = P4y - P2y;
        float gd31x = G3x - G1x, gd31y = G3y - G1y;
        float gd42x = G4x - G2x, gd42y = G4y - G2y;
        float pred_cr = fdiv_fast(norm2f(pd31x, pd31y), norm2f(pd42x, pd42y) + EPS);
        float gt_cr   = fdiv_fast(norm2f(gd31x, gd31y), norm2f(gd42x, gd42y) + EPS);
        float L_shape = fabsf(pred_cr - gt_cr);

        // ---- L_edge ----
        float v12x = P2x - P1x, v12y = P2y - P1y;
        float v23x = P3x - P2x, v23y = P3y - P2y;
        float v34x = P4x - P3x, v34y = P4y - P3y;
        float v41x = P1x - P4x, v41y = P1y - P4y;
        float l12 = norm2f(v12x, v12y), l23 = norm2f(v23x, v23y);
        float l34 = norm2f(v34x, v34y), l41 = norm2f(v41x, v41y);
        float par1 = fdiv_fast(fabsf(l12 - l34), l12 + l34 + EPS);
        float par2 = fdiv_fast(fabsf(l23 - l41), l23 + l41 + EPS);
        float dot1 = fabsf(fdiv_fast(v12x * v41x + v12y * v41y, l12 * l41 + EPS));
        float dot2 = fabsf(fdiv_fast(v12x * v23x + v12y * v23y, l12 * l23 + EPS));
        float dot3 = fabsf(fdiv_fast(v23x * v34x + v23y * v34y, l23 * l34 + EPS));
        float dot4 = fabsf(fdiv_fast(v34x * v41x + v34y * v41y, l34 * l41 + EPS));
        float L_edge = 0.5f * (par1 + par2) + 0.25f * (dot1 + dot2 + dot3 + dot4);

        // ---- L_pos ----
        float dist = 0.25f * (norm2f(P1x - G1x, P1y - G1y) +
                              norm2f(P2x - G2x, P2y - G2y) +
                              norm2f(P3x - G3x, P3y - G3y) +
                              norm2f(P4x - G4x, P4y - G4y));

        float p21x = P2x - P1x, p21y = P2y - P1y;
        float p41x = P4x - P1x, p41y = P4y - P1y;
        float g21x = G2x - G1x, g21y = G2y - G1y;
        float g41x = G4x - G1x, g41y = G4y - G1y;
        float pred_area = 0.5f * fabsf(p21x * pd31y - p21y * pd31x)
                        + 0.5f * fabsf(pd31x * p41y - pd31y * p41x);
        float gt_area   = 0.5f * fabsf(g21x * gd31y - g21y * gd31x)
                        + 0.5f * fabsf(gd31x * g41y - gd31y * g41x);
        float area_ratio = fdiv_fast(fabsf(pred_area - gt_area), gt_area + EPS);

        float mpx = 0.25f * (P1x + P2x + P3x + P4x);
        float mpy = 0.25f * (P1y + P2y + P3y + P4y);
        float mgx = 0.25f * (G1x + G2x + G3x + G4x);
        float mgy = 0.25f * (G1y + G2y + G3y + G4y);
        float rel_cons = 0.25f *
            (norm2f((P1x - mpx) - (G1x - mgx), (P1y - mpy) - (G1y - mgy)) +
             norm2f((P2x - mpx) - (G2x - mgx), (P2y - mpy) - (G2y - mgy)) +
             norm2f((P3x - mpx) - (G3x - mgx), (P3y - mpy) - (G3y - mgy)) +
             norm2f((P4x - mpx) - (G4x - mgx), (P4y - mpy) - (G4y - mgy)));

        float L_pos = 0.4f * dist + 0.3f * area_ratio + 0.3f * rel_cons;
        L = 0.4f * L_shape + 0.3f * L_edge + 0.3f * L_pos;
    }

    // ---- reduction: wave64 shuffle -> LDS -> one partial store per block ----
#pragma unroll
    for (int off = 32; off > 0; off >>= 1) {
        L     += __shfl_down(L, off, 64);
        vflag += __shfl_down(vflag, off, 64);
    }
    __shared__ float sL[4], sV[4];
    int lane = threadIdx.x & 63;
    int wv   = threadIdx.x >> 6;
    if (lane == 0) { sL[wv] = L; sV[wv] = vflag; }
    __syncthreads();
    if (threadIdx.x == 0) {
        float tL = sL[0] + sL[1] + sL[2] + sL[3];
        float tV = sV[0] + sV[1] + sV[2] + sV[3];
        partials[blockIdx.x] = make_float2(tL, tV);
    }
}

// Stage 2: reduce nPart partials in one block, write final scalar.
__global__ __launch_bounds__(256) void gsc_reduce_kernel(
    const float2* __restrict__ partials, int nPart, float* __restrict__ out)
{
    float sLsum = 0.0f, sVsum = 0.0f;
    for (int i = threadIdx.x; i < nPart; i += 256) {
        float2 p = partials[i];
        sLsum += p.x;
        sVsum += p.y;
    }
#pragma unroll
    for (int off = 32; off > 0; off >>= 1) {
        sLsum += __shfl_down(sLsum, off, 64);
        sVsum += __shfl_down(sVsum, off, 64);
    }
    __shared__ float sL[4], sV[4];
    int lane = threadIdx.x & 63;
    int wv   = threadIdx.x >> 6;
    if (lane == 0) { sL[wv] = sLsum; sV[wv] = sVsum; }
    __syncthreads();
    if (threadIdx.x == 0) {
        float tL = sL[0] + sL[1] + sL[2] + sL[3];
        float tV = sV[0] + sV[1] + sV[2] + sV[3];
        out[0] = (tV > 0.0f) ? (tL / tV) : 0.0f;
    }
}

extern "C" void kernel_launch(void* const* d_in, const int* in_sizes, int n_in,
                              void* d_out, int out_size, void* d_ws, size_t ws_size,
                              hipStream_t stream) {
    const float* pred = (const float*)d_in[0];
    const float* gt   = (const float*)d_in[1];
    float* out = (float*)d_out;
    float2* partials = (float2*)d_ws;

    int B = in_sizes[0] / 24;        // 524288 (multiple of 256)
    int grid = (B + NT - 1) / NT;

    gsc_loss_kernel<<<grid, NT, 0, stream>>>(pred, gt, partials, B);
    gsc_reduce_kernel<<<1, 256, 0, stream>>>(partials, grid, out);
}

// Round 9
// 115.350 us; speedup vs baseline: 1.0534x; 1.0102x over previous
//
#include <hip/hip_runtime.h>

#define EPS 1e-6f
#define NT  256   // threads per block
#define RPT 2     // tiles (of NT rows) per block: all loads in flight up front

__device__ __forceinline__ float fsqrt_fast(float x) {
    return __builtin_amdgcn_sqrtf(x);      // v_sqrt_f32, ~1 ulp; threshold 2.4e-2
}
__device__ __forceinline__ float fdiv_fast(float a, float b) {
    return a * __builtin_amdgcn_rcpf(b);   // v_rcp_f32 + mul
}
__device__ __forceinline__ float norm2f(float dx, float dy) {
    return fsqrt_fast(dx * dx + dy * dy);
}

// Scalar-only 8-way select (cndmask chain). Array version defeated SROA ->
// scratch spills (R1-R3: VGPR_Count=28, 20MB scratch WRITE leakage).
__device__ __forceinline__ float sel8s(int k, float v0, float v1, float v2,
                                       float v3, float v4, float v5, float v6,
                                       float v7) {
    float r = v0;
    r = (k == 1) ? v1 : r;
    r = (k == 2) ? v2 : r;
    r = (k == 3) ? v3 : r;
    r = (k == 4) ? v4 : r;
    r = (k == 5) ? v5 : r;
    r = (k == 6) ? v6 : r;
    r = (k == 7) ? v7 : r;
    return r;
}

// One tile: route 12 preloaded float4s through the shared 28.7KB padded-7
// buffer (gcd(7,8)=1 -> conflict-free ds_read_b128), compute row loss.
// Ends with a barrier so the caller can immediately reuse sT.
__device__ __forceinline__ float2 tile_body(
    float4 pr0, float4 pr1, float4 pr2, float4 pr3, float4 pr4, float4 pr5,
    float4 gr0, float4 gr1, float4 gr2, float4 gr3, float4 gr4, float4 gr5,
    float4* __restrict__ sT, int t, bool ok)
{
#define SLOT(i) (7 * ((t + (i) * NT) / 6) + ((t + (i) * NT) % 6))
    // phase 1: pred
    sT[SLOT(0)] = pr0; sT[SLOT(1)] = pr1; sT[SLOT(2)] = pr2;
    sT[SLOT(3)] = pr3; sT[SLOT(4)] = pr4; sT[SLOT(5)] = pr5;
    __syncthreads();
    float4 pA = sT[t * 7 + 0], pB = sT[t * 7 + 1], pC = sT[t * 7 + 2];
    float4 pD = sT[t * 7 + 3], pE = sT[t * 7 + 4], pF = sT[t * 7 + 5];
    __syncthreads();
    // phase 2: gt
    sT[SLOT(0)] = gr0; sT[SLOT(1)] = gr1; sT[SLOT(2)] = gr2;
    sT[SLOT(3)] = gr3; sT[SLOT(4)] = gr4; sT[SLOT(5)] = gr5;
    __syncthreads();
    float4 gA = sT[t * 7 + 0], gB = sT[t * 7 + 1], gC = sT[t * 7 + 2];
    float4 gD = sT[t * 7 + 3], gE = sT[t * 7 + 4], gF = sT[t * 7 + 5];
    __syncthreads();   // buffer free for the next tile
#undef SLOT

    float px0 = pA.x, py0 = pA.y, pz0 = pA.z;
    float px1 = pA.w, py1 = pB.x, pz1 = pB.y;
    float px2 = pB.z, py2 = pB.w, pz2 = pC.x;
    float px3 = pC.y, py3 = pC.z, pz3 = pC.w;
    float px4 = pD.x, py4 = pD.y, pz4 = pD.z;
    float px5 = pD.w, py5 = pE.x, pz5 = pE.y;
    float px6 = pE.z, py6 = pE.w, pz6 = pF.x;
    float px7 = pF.y, py7 = pF.z, pz7 = pF.w;

    float gx0 = gA.x, gy0 = gA.y, gz0 = gA.z;
    float gx1 = gA.w, gy1 = gB.x, gz1 = gB.y;
    float gx2 = gB.z, gy2 = gB.w, gz2 = gC.x;
    float gx3 = gC.y, gy3 = gC.z, gz3 = gC.w;
    float gx4 = gD.x, gy4 = gD.y, gz4 = gD.z;
    float gx5 = gD.w, gy5 = gE.x, gz5 = gE.y;
    float gx6 = gE.z, gy6 = gE.w, gz6 = gF.x;
    float gx7 = gF.y, gy7 = gF.z, gz7 = gF.w;

    float L = 0.0f, vflag = 0.0f;

    unsigned mask = 0;
    mask |= (pz0 > 0.5f && gz0 > 0.5f) ? 1u   : 0u;
    mask |= (pz1 > 0.5f && gz1 > 0.5f) ? 2u   : 0u;
    mask |= (pz2 > 0.5f && gz2 > 0.5f) ? 4u   : 0u;
    mask |= (pz3 > 0.5f && gz3 > 0.5f) ? 8u   : 0u;
    mask |= (pz4 > 0.5f && gz4 > 0.5f) ? 16u  : 0u;
    mask |= (pz5 > 0.5f && gz5 > 0.5f) ? 32u  : 0u;
    mask |= (pz6 > 0.5f && gz6 > 0.5f) ? 64u  : 0u;
    mask |= (pz7 > 0.5f && gz7 > 0.5f) ? 128u : 0u;

    if (ok && __popc(mask) >= 4) {
        vflag = 1.0f;

        unsigned m = mask;
        int k0 = __ffs(m) - 1; m &= m - 1;
        int k1 = __ffs(m) - 1; m &= m - 1;
        int k2 = __ffs(m) - 1; m &= m - 1;
        int k3 = __ffs(m) - 1;

        float P1x = sel8s(k0, px0, px1, px2, px3, px4, px5, px6, px7);
        float P1y = sel8s(k0, py0, py1, py2, py3, py4, py5, py6, py7);
        float G1x = sel8s(k0, gx0, gx1, gx2, gx3, gx4, gx5, gx6, gx7);
        float G1y = sel8s(k0, gy0, gy1, gy2, gy3, gy4, gy5, gy6, gy7);
        float P2x = sel8s(k1, px0, px1, px2, px3, px4, px5, px6, px7);
        float P2y = sel8s(k1, py0, py1, py2, py3, py4, py5, py6, py7);
        float G2x = sel8s(k1, gx0, gx1, gx2, gx3, gx4, gx5, gx6, gx7);
        float G2y = sel8s(k1, gy0, gy1, gy2, gy3, gy4, gy5, gy6, gy7);
        float P3x = sel8s(k2, px0, px1, px2, px3, px4, px5, px6, px7);
        float P3y = sel8s(k2, py0, py1, py2, py3, py4, py5, py6, py7);
        float G3x = sel8s(k2, gx0, gx1, gx2, gx3, gx4, gx5, gx6, gx7);
        float G3y = sel8s(k2, gy0, gy1, gy2, gy3, gy4, gy5, gy6, gy7);
        float P4x = sel8s(k3, px0, px1, px2, px3, px4, px5, px6, px7);
        float P4y = sel8s(k3, py0, py1, py2, py3, py4, py5, py6, py7);
        float G4x = sel8s(k3, gx0, gx1, gx2, gx3, gx4, gx5, gx6, gx7);
        float G4y = sel8s(k3, gy0, gy1, gy2, gy3, gy4, gy5, gy6, gy7);

        // ---- L_shape ----
        float pd31x = P3x - P1x, pd31y = P3y - P1y;
        float pd42x = P4x - P2x, pd42y = P4y - P2y;
        float gd31x = G3x - G1x, gd31y = G3y - G1y;
        float gd42x = G4x - G2x, gd42y = G4y - G2y;
        float pred_cr = fdiv_fast(norm2f(pd31x, pd31y), norm2f(pd42x, pd42y) + EPS);
        float gt_cr   = fdiv_fast(norm2f(gd31x, gd31y), norm2f(gd42x, gd42y) + EPS);
        float L_shape = fabsf(pred_cr - gt_cr);

        // ---- L_edge ----
        float v12x = P2x - P1x, v12y = P2y - P1y;
        float v23x = P3x - P2x, v23y = P3y - P2y;
        float v34x = P4x - P3x, v34y = P4y - P3y;
        float v41x = P1x - P4x, v41y = P1y - P4y;
        float l12 = norm2f(v12x, v12y), l23 = norm2f(v23x, v23y);
        float l34 = norm2f(v34x, v34y), l41 = norm2f(v41x, v41y);
        float par1 = fdiv_fast(fabsf(l12 - l34), l12 + l34 + EPS);
        float par2 = fdiv_fast(fabsf(l23 - l41), l23 + l41 + EPS);
        float dot1 = fabsf(fdiv_fast(v12x * v41x + v12y * v41y, l12 * l41 + EPS));
        float dot2 = fabsf(fdiv_fast(v12x * v23x + v12y * v23y, l12 * l23 + EPS));
        float dot3 = fabsf(fdiv_fast(v23x * v34x + v23y * v34y, l23 * l34 + EPS));
        float dot4 = fabsf(fdiv_fast(v34x * v41x + v34y * v41y, l34 * l41 + EPS));
        float L_edge = 0.5f * (par1 + par2) + 0.25f * (dot1 + dot2 + dot3 + dot4);

        // ---- L_pos ----
        float dist = 0.25f * (norm2f(P1x - G1x, P1y - G1y) +
                              norm2f(P2x - G2x, P2y - G2y) +
                              norm2f(P3x - G3x, P3y - G3y) +
                              norm2f(P4x - G4x, P4y - G4y));

        float p21x = P2x - P1x, p21y = P2y - P1y;
        float p41x = P4x - P1x, p41y = P4y - P1y;
        float g21x = G2x - G1x, g21y = G2y - G1y;
        float g41x = G4x - G1x, g41y = G4y - G1y;
        float pred_area = 0.5f * fabsf(p21x * pd31y - p21y * pd31x)
                        + 0.5f * fabsf(pd31x * p41y - pd31y * p41x);
        float gt_area   = 0.5f * fabsf(g21x * gd31y - g21y * gd31x)
                        + 0.5f * fabsf(gd31x * g41y - gd31y * g41x);
        float area_ratio = fdiv_fast(fabsf(pred_area - gt_area), gt_area + EPS);

        float mpx = 0.25f * (P1x + P2x + P3x + P4x);
        float mpy = 0.25f * (P1y + P2y + P3y + P4y);
        float mgx = 0.25f * (G1x + G2x + G3x + G4x);
        float mgy = 0.25f * (G1y + G2y + G3y + G4y);
        float rel_cons = 0.25f *
            (norm2f((P1x - mpx) - (G1x - mgx), (P1y - mpy) - (G1y - mgy)) +
             norm2f((P2x - mpx) - (G2x - mgx), (P2y - mpy) - (G2y - mgy)) +
             norm2f((P3x - mpx) - (G3x - mgx), (P3y - mpy) - (G3y - mgy)) +
             norm2f((P4x - mpx) - (G4x - mgx), (P4y - mpy) - (G4y - mgy)));

        float L_pos = 0.4f * dist + 0.3f * area_ratio + 0.3f * rel_cons;
        L = 0.4f * L_shape + 0.3f * L_edge + 0.3f * L_pos;
    }
    return make_float2(L, vflag);
}

__global__ __launch_bounds__(256) void gsc_loss_kernel(
    const float* __restrict__ pred, const float* __restrict__ gt,
    float2* __restrict__ partials, int B)
{
    __shared__ float4 sT[NT * 7];    // 28.7 KB, shared by both tiles
    const int t = threadIdx.x;
    const size_t base = (size_t)blockIdx.x * (NT * RPT);
    const size_t maxf = (size_t)B * 6 - 1;   // clamp for safety (B%512==0 in practice)

    const float4* p4 = reinterpret_cast<const float4*>(pred);
    const float4* g4 = reinterpret_cast<const float4*>(gt);
    const size_t f0 = base * 6;
    const size_t f1 = (base + NT) * 6;
    const bool ok0 = (base + t) < (size_t)B;
    const bool ok1 = (base + NT + t) < (size_t)B;

#define CL(x) ((x) <= maxf ? (x) : maxf)
    // ---- ALL 24 coalesced loads in flight before any compute (24 KB/wave):
    // tile-1's HBM latency hides under tile-0's LDS/compute phase.
    float4 ap0 = p4[CL(f0 + t + 0 * NT)], ap1 = p4[CL(f0 + t + 1 * NT)];
    float4 ap2 = p4[CL(f0 + t + 2 * NT)], ap3 = p4[CL(f0 + t + 3 * NT)];
    float4 ap4 = p4[CL(f0 + t + 4 * NT)], ap5 = p4[CL(f0 + t + 5 * NT)];
    float4 ag0 = g4[CL(f0 + t + 0 * NT)], ag1 = g4[CL(f0 + t + 1 * NT)];
    float4 ag2 = g4[CL(f0 + t + 2 * NT)], ag3 = g4[CL(f0 + t + 3 * NT)];
    float4 ag4 = g4[CL(f0 + t + 4 * NT)], ag5 = g4[CL(f0 + t + 5 * NT)];
    float4 bp0 = p4[CL(f1 + t + 0 * NT)], bp1 = p4[CL(f1 + t + 1 * NT)];
    float4 bp2 = p4[CL(f1 + t + 2 * NT)], bp3 = p4[CL(f1 + t + 3 * NT)];
    float4 bp4 = p4[CL(f1 + t + 4 * NT)], bp5 = p4[CL(f1 + t + 5 * NT)];
    float4 bg0 = g4[CL(f1 + t + 0 * NT)], bg1 = g4[CL(f1 + t + 1 * NT)];
    float4 bg2 = g4[CL(f1 + t + 2 * NT)], bg3 = g4[CL(f1 + t + 3 * NT)];
    float4 bg4 = g4[CL(f1 + t + 4 * NT)], bg5 = g4[CL(f1 + t + 5 * NT)];
#undef CL

    float2 r0 = tile_body(ap0, ap1, ap2, ap3, ap4, ap5,
                          ag0, ag1, ag2, ag3, ag4, ag5, sT, t, ok0);
    float2 r1 = tile_body(bp0, bp1, bp2, bp3, bp4, bp5,
                          bg0, bg1, bg2, bg3, bg4, bg5, sT, t, ok1);

    float L     = r0.x + r1.x;
    float vflag = r0.y + r1.y;

    // ---- reduction: wave64 shuffle -> LDS -> one partial store per block ----
#pragma unroll
    for (int off = 32; off > 0; off >>= 1) {
        L     += __shfl_down(L, off, 64);
        vflag += __shfl_down(vflag, off, 64);
    }
    __shared__ float sL[4], sV[4];
    int lane = threadIdx.x & 63;
    int wv   = threadIdx.x >> 6;
    if (lane == 0) { sL[wv] = L; sV[wv] = vflag; }
    __syncthreads();
    if (threadIdx.x == 0) {
        float tL = sL[0] + sL[1] + sL[2] + sL[3];
        float tV = sV[0] + sV[1] + sV[2] + sV[3];
        partials[blockIdx.x] = make_float2(tL, tV);
    }
}

// Stage 2: reduce nPart partials in one block, write final scalar.
__global__ __launch_bounds__(256) void gsc_reduce_kernel(
    const float2* __restrict__ partials, int nPart, float* __restrict__ out)
{
    float sLsum = 0.0f, sVsum = 0.0f;
    for (int i = threadIdx.x; i < nPart; i += 256) {
        float2 p = partials[i];
        sLsum += p.x;
        sVsum += p.y;
    }
#pragma unroll
    for (int off = 32; off > 0; off >>= 1) {
        sLsum += __shfl_down(sLsum, off, 64);
        sVsum += __shfl_down(sVsum, off, 64);
    }
    __shared__ float sL[4], sV[4];
    int lane = threadIdx.x & 63;
    int wv   = threadIdx.x >> 6;
    if (lane == 0) { sL[wv] = sLsum; sV[wv] = sVsum; }
    __syncthreads();
    if (threadIdx.x == 0) {
        float tL = sL[0] + sL[1] + sL[2] + sL[3];
        float tV = sV[0] + sV[1] + sV[2] + sV[3];
        out[0] = (tV > 0.0f) ? (tL / tV) : 0.0f;
    }
}

extern "C" void kernel_launch(void* const* d_in, const int* in_sizes, int n_in,
                              void* d_out, int out_size, void* d_ws, size_t ws_size,
                              hipStream_t stream) {
    const float* pred = (const float*)d_in[0];
    const float* gt   = (const float*)d_in[1];
    float* out = (float*)d_out;
    float2* partials = (float2*)d_ws;

    int B = in_sizes[0] / 24;                    // 524288
    int grid = (B + NT * RPT - 1) / (NT * RPT);  // 1024

    gsc_loss_kernel<<<grid, NT, 0, stream>>>(pred, gt, partials, B);
    gsc_reduce_kernel<<<1, 256, 0, stream>>>(partials, grid, out);
}